// Round 1
// baseline (773.279 us; speedup 1.0000x reference)
//
#include <hip/hip_runtime.h>
#include <math.h>

#define S_LEN 4096
#define D_IN 256
#define D_OUT 64
#define BATCH 4

#define BQ 32     // query rows per block
#define BK 64     // key rows per tile
#define RPW 8     // query rows per wave (4 waves * 8 = 32)

// ---------------- projection: C[M][64] = X[M][256] @ W[256][64], M = B*S ----
__global__ __launch_bounds__(256) void proj_kernel(
    const float* __restrict__ Xq, const float* __restrict__ Xk, const float* __restrict__ Xv,
    const float* __restrict__ wq, const float* __restrict__ wk, const float* __restrict__ wv,
    float* __restrict__ Qb, float* __restrict__ Kb, float* __restrict__ Vb)
{
    const float* X; const float* W; float* C;
    if (blockIdx.y == 0)      { X = Xq; W = wq; C = Qb; }
    else if (blockIdx.y == 1) { X = Xk; W = wk; C = Kb; }
    else                      { X = Xv; W = wv; C = Vb; }

    __shared__ float Xs[64][64];
    __shared__ float Ws[64][64];

    const int t    = threadIdx.x;
    const int c    = t & 63;       // output column (lane)
    const int rgrp = t >> 6;       // wave id 0..3 -> rows rgrp*16 .. +15
    const int row0 = blockIdx.x * 64;

    float acc[16];
#pragma unroll
    for (int i = 0; i < 16; ++i) acc[i] = 0.f;

    for (int kt = 0; kt < 4; ++kt) {
        __syncthreads();
        // stage X tile [64][64] and W tile [64][64]
#pragma unroll
        for (int i = 0; i < 4; ++i) {
            int idx = (t + i * 256) * 4;          // 0..16380 step 4
            int r = idx >> 6, cc = idx & 63;
            *reinterpret_cast<float4*>(&Xs[r][cc]) =
                *reinterpret_cast<const float4*>(&X[(size_t)(row0 + r) * D_IN + kt * 64 + cc]);
            *reinterpret_cast<float4*>(&Ws[r][cc]) =
                *reinterpret_cast<const float4*>(&W[(size_t)(kt * 64 + r) * D_OUT + cc]);
        }
        __syncthreads();

        for (int kk = 0; kk < 64; kk += 4) {
            const float w0 = Ws[kk + 0][c];
            const float w1 = Ws[kk + 1][c];
            const float w2 = Ws[kk + 2][c];
            const float w3 = Ws[kk + 3][c];
#pragma unroll
            for (int i = 0; i < 16; ++i) {
                const float4 x = *reinterpret_cast<const float4*>(&Xs[rgrp * 16 + i][kk]);
                acc[i] += x.x * w0 + x.y * w1 + x.z * w2 + x.w * w3;
            }
        }
    }

#pragma unroll
    for (int i = 0; i < 16; ++i)
        C[(size_t)(row0 + rgrp * 16 + i) * D_OUT + c] = acc[i];
}

// ---------------- causal flash attention, fp32 -----------------------------
__global__ __launch_bounds__(256) void attn_kernel(
    const float* __restrict__ Q, const float* __restrict__ K, const float* __restrict__ V,
    float* __restrict__ O)
{
    __shared__ float Ks[BK][68];          // +4 pad: 16B-aligned rows, balanced banks
    __shared__ float Vs[BK][68];
    __shared__ float Qs[BQ][64];
    __shared__ float Ps[4][RPW][68];      // per-wave P broadcast buffer

    const int t    = threadIdx.x;
    const int lane = t & 63;
    const int wid  = t >> 6;

    // longest q-tiles scheduled first (causal load balance)
    const int b     = blockIdx.x & 3;
    const int revqt = blockIdx.x >> 2;                  // 0..127
    const int q0    = S_LEN - BQ * (revqt + 1);         // 4064, 4032, ... 0

    const float* Qp = Q + (size_t)b * S_LEN * D_OUT;
    const float* Kp = K + (size_t)b * S_LEN * D_OUT;
    const float* Vp = V + (size_t)b * S_LEN * D_OUT;

    // stage Q rows [BQ][64]
#pragma unroll
    for (int i = 0; i < 2; ++i) {
        int idx = (t + i * 256) * 4;      // 0..2044
        int r = idx >> 6, cc = idx & 63;
        *reinterpret_cast<float4*>(&Qs[r][cc]) =
            *reinterpret_cast<const float4*>(&Qp[(size_t)(q0 + r) * D_OUT + cc]);
    }

    float Oacc[RPW], m[RPW], l[RPW];
#pragma unroll
    for (int r = 0; r < RPW; ++r) { Oacc[r] = 0.f; m[r] = -1e30f; l[r] = 0.f; }

    const int row0   = q0 + wid * RPW;
    const int ntiles = (q0 + BQ + BK - 1) / BK;   // covers keys 0 .. q0+BQ-1

    for (int kt = 0; kt < ntiles; ++kt) {
        const int k0 = kt * BK;
        __syncthreads();
        // stage K,V tile [BK][64]
#pragma unroll
        for (int i = 0; i < 4; ++i) {
            int idx = (t + i * 256) * 4;
            int r = idx >> 6, cc = idx & 63;
            *reinterpret_cast<float4*>(&Ks[r][cc]) =
                *reinterpret_cast<const float4*>(&Kp[(size_t)(k0 + r) * D_OUT + cc]);
            *reinterpret_cast<float4*>(&Vs[r][cc]) =
                *reinterpret_cast<const float4*>(&Vp[(size_t)(k0 + r) * D_OUT + cc]);
        }
        __syncthreads();

        // ---- QK^T: lane j owns key k0+j; s[r] = score(row0+r, k0+j)
        float s[RPW];
#pragma unroll
        for (int r = 0; r < RPW; ++r) s[r] = 0.f;
        for (int d = 0; d < 64; d += 4) {
            const float4 kv = *reinterpret_cast<const float4*>(&Ks[lane][d]);
#pragma unroll
            for (int r = 0; r < RPW; ++r) {
                const float4 qv = *reinterpret_cast<const float4*>(&Qs[wid * RPW + r][d]);
                s[r] += qv.x * kv.x + qv.y * kv.y + qv.z * kv.z + qv.w * kv.w;
            }
        }

        // ---- mask + online softmax
        const int kcol = k0 + lane;
#pragma unroll
        for (int r = 0; r < RPW; ++r) {
            const int qrow = row0 + r;
            float sv = (kcol <= qrow) ? s[r] * 0.125f : -1e30f;
            float mx = sv;
#pragma unroll
            for (int off = 32; off; off >>= 1) mx = fmaxf(mx, __shfl_xor(mx, off, 64));
            const float mnew  = fmaxf(m[r], mx);
            const float alpha = __expf(m[r] - mnew);
            const float pv    = __expf(sv - mnew);
            float sum = pv;
#pragma unroll
            for (int off = 32; off; off >>= 1) sum += __shfl_xor(sum, off, 64);
            l[r]    = l[r] * alpha + sum;
            Oacc[r] = Oacc[r] * alpha;
            m[r]    = mnew;
            Ps[wid][r][lane] = pv;        // wave-local: no barrier needed
        }

        // ---- PV: lane d owns output dim d
        for (int j = 0; j < BK; j += 4) {
            const float v0 = Vs[j + 0][lane];
            const float v1 = Vs[j + 1][lane];
            const float v2 = Vs[j + 2][lane];
            const float v3 = Vs[j + 3][lane];
#pragma unroll
            for (int r = 0; r < RPW; ++r) {
                const float4 pj = *reinterpret_cast<const float4*>(&Ps[wid][r][j]);
                Oacc[r] += pj.x * v0 + pj.y * v1 + pj.z * v2 + pj.w * v3;
            }
        }
    }

#pragma unroll
    for (int r = 0; r < RPW; ++r) {
        const int qrow = row0 + r;
        O[((size_t)b * S_LEN + qrow) * D_OUT + lane] = Oacc[r] / l[r];
    }
}

extern "C" void kernel_launch(void* const* d_in, const int* in_sizes, int n_in,
                              void* d_out, int out_size, void* d_ws, size_t ws_size,
                              hipStream_t stream) {
    // setup_inputs() order: keys-X, values-X, queries-X, wq, wk, wv
    const float* Xk = (const float*)d_in[0];
    const float* Xv = (const float*)d_in[1];
    const float* Xq = (const float*)d_in[2];
    const float* wq = (const float*)d_in[3];
    const float* wk = (const float*)d_in[4];
    const float* wv = (const float*)d_in[5];
    float* out = (float*)d_out;

    // workspace: Q | K | V, each B*S*D_OUT f32 = 4 MiB (12 MiB total)
    float* Qb = (float*)d_ws;
    float* Kb = Qb + (size_t)BATCH * S_LEN * D_OUT;
    float* Vb = Kb + (size_t)BATCH * S_LEN * D_OUT;

    dim3 pgrid(BATCH * S_LEN / 64, 3);
    proj_kernel<<<pgrid, 256, 0, stream>>>(Xq, Xk, Xv, wq, wk, wv, Qb, Kb, Vb);

    attn_kernel<<<BATCH * (S_LEN / BQ), 256, 0, stream>>>(Qb, Kb, Vb, out);
}

// Round 2
// 208.502 us; speedup vs baseline: 3.7087x; 3.7087x over previous
//
#include <hip/hip_runtime.h>

#define S_LEN 4096
#define D_IN 256
#define D_OUT 64
#define BATCH 4
#define BQ 32

typedef short bf16x8 __attribute__((ext_vector_type(8)));
typedef float f32x4 __attribute__((ext_vector_type(4)));

union L16 { int4 i; bf16x8 s; };

// byte offset into a [rows][64] bf16 tile (128 B rows, 8x 16B chunks),
// XOR-swizzled per guide G4: chunk ^= (row & 7)
#define SWZ(row, chunk) (((row) << 7) + ((((chunk) ^ ((row) & 7))) << 4))

__device__ inline ushort f2bf(float x) {
    unsigned u = __builtin_bit_cast(unsigned, x);
    u += 0x7FFFu + ((u >> 16) & 1u);     // RNE
    return (ushort)(u >> 16);
}

// ---------------- projection: bf16 Q,K [b*s][64]; bf16 V^T [b][64][s] -------
__global__ __launch_bounds__(256) void proj_kernel(
    const float* __restrict__ Xq, const float* __restrict__ Xk, const float* __restrict__ Xv,
    const float* __restrict__ wq, const float* __restrict__ wk, const float* __restrict__ wv,
    ushort* __restrict__ Qb, ushort* __restrict__ Kb, ushort* __restrict__ Vtb)
{
    const float* X; const float* W;
    if (blockIdx.y == 0)      { X = Xq; W = wq; }
    else if (blockIdx.y == 1) { X = Xk; W = wk; }
    else                      { X = Xv; W = wv; }

    __shared__ float  Xs[64][64];
    __shared__ float  Ws[64][64];
    __shared__ ushort Ts[64][72];   // bf16 transpose bounce (V only), +8 pad

    const int t    = threadIdx.x;
    const int c    = t & 63;        // output column
    const int rgrp = t >> 6;        // wave id -> rows rgrp*16..+15
    const int row0 = blockIdx.x * 64;

    float acc[16];
#pragma unroll
    for (int i = 0; i < 16; ++i) acc[i] = 0.f;

    for (int kt = 0; kt < 4; ++kt) {
        __syncthreads();
#pragma unroll
        for (int i = 0; i < 4; ++i) {
            int idx = (t + i * 256) * 4;
            int r = idx >> 6, cc = idx & 63;
            *reinterpret_cast<float4*>(&Xs[r][cc]) =
                *reinterpret_cast<const float4*>(&X[(size_t)(row0 + r) * D_IN + kt * 64 + cc]);
            *reinterpret_cast<float4*>(&Ws[r][cc]) =
                *reinterpret_cast<const float4*>(&W[(size_t)(kt * 64 + r) * D_OUT + cc]);
        }
        __syncthreads();

        for (int kk = 0; kk < 64; kk += 4) {
            const float w0 = Ws[kk + 0][c];
            const float w1 = Ws[kk + 1][c];
            const float w2 = Ws[kk + 2][c];
            const float w3 = Ws[kk + 3][c];
#pragma unroll
            for (int i = 0; i < 16; ++i) {
                const float4 x = *reinterpret_cast<const float4*>(&Xs[rgrp * 16 + i][kk]);
                acc[i] += x.x * w0 + x.y * w1 + x.z * w2 + x.w * w3;
            }
        }
    }

    if (blockIdx.y < 2) {
        ushort* C = (blockIdx.y == 0) ? Qb : Kb;
#pragma unroll
        for (int i = 0; i < 16; ++i)
            C[(size_t)(row0 + rgrp * 16 + i) * D_OUT + c] = f2bf(acc[i]);
    } else {
        __syncthreads();
#pragma unroll
        for (int i = 0; i < 16; ++i)
            Ts[c][rgrp * 16 + i] = f2bf(acc[i]);     // transpose: Ts[e][s_local]
        __syncthreads();
        const int b  = row0 >> 12;
        const int s0 = row0 & 4095;
        const int d  = t >> 2;
#pragma unroll
        for (int q = 0; q < 2; ++q) {
            int ch = (t & 3) * 2 + q;                // 16B chunks of the d-row
            int4 v = *reinterpret_cast<const int4*>(&Ts[d][ch * 8]);
            *reinterpret_cast<int4*>(&Vtb[((size_t)b * 64 + d) * S_LEN + s0 + ch * 8]) = v;
        }
    }
}

// ---------------- causal flash attention, bf16 MFMA -------------------------
// 2 waves/block, wave w owns q-rows q0+16w .. +15 (M=16 MFMA tiles), KV tile 64
__global__ __launch_bounds__(128) void attn_kernel(
    const ushort* __restrict__ Q, const ushort* __restrict__ K,
    const ushort* __restrict__ Vt, float* __restrict__ O)
{
    __shared__ ushort Ks[64 * 64];       // K tile  [key][d], swizzled
    __shared__ ushort Vs[64 * 64];       // V^T tile [d][key], swizzled
    __shared__ ushort Ps[2 * 16 * 64];   // per-wave P [q][key], swizzled

    const int t    = threadIdx.x;
    const int lane = t & 63;
    const int w    = t >> 6;
    const int n    = lane & 15;
    const int g    = lane >> 4;

    // reverse-q order: longest blocks dispatched first (LPT balance)
    const int b  = blockIdx.x & 3;
    const int q0 = S_LEN - BQ * ((blockIdx.x >> 2) + 1);

    const ushort* Qp = Q  + (size_t)b * S_LEN * 64;
    const ushort* Kp = K  + (size_t)b * S_LEN * 64;
    const ushort* Vp = Vt + (size_t)b * 64 * S_LEN;

    char* KsB = (char*)Ks;
    char* VsB = (char*)Vs;
    char* PsB = (char*)Ps + w * 2048;

    // Q A-frags (layout: row = lane&15, k = 32h + 8*(lane>>4) + i)
    L16 aq0, aq1;
    aq0.i = *reinterpret_cast<const int4*>(&Qp[(size_t)(q0 + 16 * w + n) * 64 + 8 * g]);
    aq1.i = *reinterpret_cast<const int4*>(&Qp[(size_t)(q0 + 16 * w + n) * 64 + 32 + 8 * g]);

    f32x4 oacc[4];
    float mrow[4], lrow[4];
    const f32x4 zero4 = {0.f, 0.f, 0.f, 0.f};
#pragma unroll
    for (int j = 0; j < 4; ++j) { oacc[j] = zero4; mrow[j] = -1e30f; lrow[j] = 0.f; }

    const int ntiles = (q0 + BQ + 63) >> 6;
    const int wqmin  = q0 + 16 * w;
    const int wqmax  = wqmin + 15;

    for (int kt = 0; kt < ntiles; ++kt) {
        const int k0 = kt << 6;
        __syncthreads();
        // stage K tile + V^T tile: global bf16 16B chunks -> swizzled LDS
#pragma unroll
        for (int r4 = 0; r4 < 4; ++r4) {
            int ch  = t + (r4 << 7);                 // 0..511
            int row = ch >> 3, c = ch & 7;
            int4 kv = *reinterpret_cast<const int4*>(&Kp[(size_t)(k0 + row) * 64 + c * 8]);
            int4 vv = *reinterpret_cast<const int4*>(&Vp[(size_t)row * S_LEN + k0 + c * 8]);
            *reinterpret_cast<int4*>(KsB + SWZ(row, c)) = kv;
            *reinterpret_cast<int4*>(VsB + SWZ(row, c)) = vv;
        }
        __syncthreads();
        if (k0 > wqmax) continue;   // fully-masked for this wave (barrier already done)

        // ---- QK^T: cS[t4] = S[16q x 16k], rows=q (C/D: row=(g)*4+j, col=n)
        f32x4 cS[4];
#pragma unroll
        for (int t4 = 0; t4 < 4; ++t4) {
            L16 b0, b1;
            b0.i = *reinterpret_cast<const int4*>(KsB + SWZ(16 * t4 + n, g));
            b1.i = *reinterpret_cast<const int4*>(KsB + SWZ(16 * t4 + n, 4 + g));
            f32x4 z = zero4;
            z      = __builtin_amdgcn_mfma_f32_16x16x32_bf16(aq0.s, b0.s, z, 0, 0, 0);
            cS[t4] = __builtin_amdgcn_mfma_f32_16x16x32_bf16(aq1.s, b1.s, z, 0, 0, 0);
        }

        // ---- scale + causal mask
        float sc[4][4];
#pragma unroll
        for (int t4 = 0; t4 < 4; ++t4)
#pragma unroll
            for (int j = 0; j < 4; ++j) sc[t4][j] = cS[t4][j] * 0.125f;

        if (k0 + 63 > wqmin) {
#pragma unroll
            for (int t4 = 0; t4 < 4; ++t4) {
                const int key = k0 + 16 * t4 + n;
#pragma unroll
                for (int j = 0; j < 4; ++j) {
                    const int q = wqmin + 4 * g + j;
                    if (key > q) sc[t4][j] = -1e30f;
                }
            }
        }

        // ---- online softmax (row = 4g+j; reduce over the 16 lanes of group g)
#pragma unroll
        for (int j = 0; j < 4; ++j) {
            float mx = fmaxf(fmaxf(sc[0][j], sc[1][j]), fmaxf(sc[2][j], sc[3][j]));
#pragma unroll
            for (int off = 1; off <= 8; off <<= 1) mx = fmaxf(mx, __shfl_xor(mx, off, 64));
            const float mnew  = fmaxf(mrow[j], mx);
            const float alpha = __expf(mrow[j] - mnew);
            const int   qrow  = 4 * g + j;
            float ps = 0.f;
#pragma unroll
            for (int t4 = 0; t4 < 4; ++t4) {
                const float p = __expf(sc[t4][j] - mnew);
                ps += p;
                *reinterpret_cast<ushort*>(PsB + SWZ(qrow, 2 * t4 + (n >> 3)) + (n & 7) * 2) = f2bf(p);
            }
#pragma unroll
            for (int off = 1; off <= 8; off <<= 1) ps += __shfl_xor(ps, off, 64);
            lrow[j] = lrow[j] * alpha + ps;
            mrow[j] = mnew;
            oacc[0][j] *= alpha; oacc[1][j] *= alpha;
            oacc[2][j] *= alpha; oacc[3][j] *= alpha;
        }

        // ---- PV: O[16q x 64d] += P[16q x 64k] * V[64k x 64d]
        asm volatile("s_waitcnt lgkmcnt(0)" ::: "memory");   // P writes -> A-frag reads
        L16 pa0, pa1;
        pa0.i = *reinterpret_cast<const int4*>(PsB + SWZ(n, g));
        pa1.i = *reinterpret_cast<const int4*>(PsB + SWZ(n, 4 + g));
#pragma unroll
        for (int nt = 0; nt < 4; ++nt) {
            L16 bv0, bv1;
            bv0.i = *reinterpret_cast<const int4*>(VsB + SWZ(16 * nt + n, g));
            bv1.i = *reinterpret_cast<const int4*>(VsB + SWZ(16 * nt + n, 4 + g));
            oacc[nt] = __builtin_amdgcn_mfma_f32_16x16x32_bf16(pa0.s, bv0.s, oacc[nt], 0, 0, 0);
            oacc[nt] = __builtin_amdgcn_mfma_f32_16x16x32_bf16(pa1.s, bv1.s, oacc[nt], 0, 0, 0);
        }
    }

    // ---- epilogue: O = oacc / l
#pragma unroll
    for (int j = 0; j < 4; ++j) {
        const float inv = 1.f / lrow[j];
        const int   q   = q0 + 16 * w + 4 * g + j;
#pragma unroll
        for (int nt = 0; nt < 4; ++nt)
            O[((size_t)b * S_LEN + q) * 64 + 16 * nt + n] = oacc[nt][j] * inv;
    }
}

extern "C" void kernel_launch(void* const* d_in, const int* in_sizes, int n_in,
                              void* d_out, int out_size, void* d_ws, size_t ws_size,
                              hipStream_t stream) {
    // setup_inputs() order: keys-X, values-X, queries-X, wq, wk, wv
    const float* Xk = (const float*)d_in[0];
    const float* Xv = (const float*)d_in[1];
    const float* Xq = (const float*)d_in[2];
    const float* wq = (const float*)d_in[3];
    const float* wk = (const float*)d_in[4];
    const float* wv = (const float*)d_in[5];
    float* out = (float*)d_out;

    // workspace: Q bf16 | K bf16 | V^T bf16  (2 MiB each)
    ushort* Qb  = (ushort*)d_ws;
    ushort* Kb  = Qb + (size_t)BATCH * S_LEN * D_OUT;
    ushort* Vtb = Kb + (size_t)BATCH * S_LEN * D_OUT;

    dim3 pgrid(BATCH * S_LEN / 64, 3);
    proj_kernel<<<pgrid, 256, 0, stream>>>(Xq, Xk, Xv, wq, wk, wv, Qb, Kb, Vtb);

    attn_kernel<<<BATCH * (S_LEN / BQ), 128, 0, stream>>>(Qb, Kb, Vtb, out);
}

// Round 3
// 99.458 us; speedup vs baseline: 7.7749x; 2.0964x over previous
//
#include <hip/hip_runtime.h>

#define S_LEN 4096
#define D_IN 256
#define D_OUT 64
#define BATCH 4
#define BQ 32
#define NQT (S_LEN / BQ)   // 128 q-tiles per batch

typedef short bf16x8 __attribute__((ext_vector_type(8)));
typedef float f32x4 __attribute__((ext_vector_type(4)));

union L16 { int4 i; bf16x8 s; };

// byte offset into a [rows][64] bf16 tile (128 B rows, 8x 16B chunks),
// XOR-swizzled per guide G4: chunk ^= (row & 7)
#define SWZ(row, chunk) (((row) << 7) + ((((chunk) ^ ((row) & 7))) << 4))

__device__ inline ushort f2bf(float x) {
    unsigned u = __builtin_bit_cast(unsigned, x);
    u += 0x7FFFu + ((u >> 16) & 1u);     // RNE
    return (ushort)(u >> 16);
}

// ---------------- projection: bf16 Q,K [b*s][64]; bf16 V^T [b][64][s] -------
__global__ __launch_bounds__(256) void proj_kernel(
    const float* __restrict__ Xq, const float* __restrict__ Xk, const float* __restrict__ Xv,
    const float* __restrict__ wq, const float* __restrict__ wk, const float* __restrict__ wv,
    ushort* __restrict__ Qb, ushort* __restrict__ Kb, ushort* __restrict__ Vtb)
{
    const float* X; const float* W;
    if (blockIdx.y == 0)      { X = Xq; W = wq; }
    else if (blockIdx.y == 1) { X = Xk; W = wk; }
    else                      { X = Xv; W = wv; }

    __shared__ float  Xs[64][64];
    __shared__ float  Ws[64][64];
    __shared__ ushort Ts[64][72];   // bf16 transpose bounce (V only), +8 pad

    const int t    = threadIdx.x;
    const int c    = t & 63;        // output column
    const int rgrp = t >> 6;        // wave id -> rows rgrp*16..+15
    const int row0 = blockIdx.x * 64;

    float acc[16];
#pragma unroll
    for (int i = 0; i < 16; ++i) acc[i] = 0.f;

    for (int kt = 0; kt < 4; ++kt) {
        __syncthreads();
#pragma unroll
        for (int i = 0; i < 4; ++i) {
            int idx = (t + i * 256) * 4;
            int r = idx >> 6, cc = idx & 63;
            *reinterpret_cast<float4*>(&Xs[r][cc]) =
                *reinterpret_cast<const float4*>(&X[(size_t)(row0 + r) * D_IN + kt * 64 + cc]);
            *reinterpret_cast<float4*>(&Ws[r][cc]) =
                *reinterpret_cast<const float4*>(&W[(size_t)(kt * 64 + r) * D_OUT + cc]);
        }
        __syncthreads();

        for (int kk = 0; kk < 64; kk += 4) {
            const float w0 = Ws[kk + 0][c];
            const float w1 = Ws[kk + 1][c];
            const float w2 = Ws[kk + 2][c];
            const float w3 = Ws[kk + 3][c];
#pragma unroll
            for (int i = 0; i < 16; ++i) {
                const float4 x = *reinterpret_cast<const float4*>(&Xs[rgrp * 16 + i][kk]);
                acc[i] += x.x * w0 + x.y * w1 + x.z * w2 + x.w * w3;
            }
        }
    }

    if (blockIdx.y < 2) {
        ushort* C = (blockIdx.y == 0) ? Qb : Kb;
#pragma unroll
        for (int i = 0; i < 16; ++i)
            C[(size_t)(row0 + rgrp * 16 + i) * D_OUT + c] = f2bf(acc[i]);
    } else {
        __syncthreads();
#pragma unroll
        for (int i = 0; i < 16; ++i)
            Ts[c][rgrp * 16 + i] = f2bf(acc[i]);     // transpose: Ts[e][s_local]
        __syncthreads();
        const int b  = row0 >> 12;
        const int s0 = row0 & 4095;
        const int d  = t >> 2;
#pragma unroll
        for (int q = 0; q < 2; ++q) {
            int ch = (t & 3) * 2 + q;                // 16B chunks of the d-row
            int4 v = *reinterpret_cast<const int4*>(&Ts[d][ch * 8]);
            *reinterpret_cast<int4*>(&Vtb[((size_t)b * 64 + d) * S_LEN + s0 + ch * 8]) = v;
        }
    }
}

// ---------------- causal flash attention, bf16 MFMA, split-K ----------------
// grid = (BATCH*NQT, NCH); block (b,qt,ch) processes q-rows [q0,q0+32) against
// keys [ch*chunk, min((ch+1)*chunk, q0+32)). Partial (O,m,l) -> ws unless the
// q-tile fits a single chunk (then direct normalized write).
__global__ __launch_bounds__(128) void attn_kernel(
    const ushort* __restrict__ Q, const ushort* __restrict__ K,
    const ushort* __restrict__ Vt, float* __restrict__ O,
    float* __restrict__ Opart, float* __restrict__ Mpart, float* __restrict__ Lpart,
    int chunk_keys, int NCH)
{
    __shared__ ushort Ks[64 * 64];       // K tile  [key][d], swizzled
    __shared__ ushort Vs[64 * 64];       // V^T tile [d][key], swizzled
    __shared__ ushort Ps[2 * 16 * 64];   // per-wave P [q][key], swizzled

    const int b  = blockIdx.x & 3;
    const int qt = blockIdx.x >> 2;
    const int q0 = qt * BQ;
    const int c0 = blockIdx.y * chunk_keys;
    if (c0 >= q0 + BQ) return;           // chunk entirely above diagonal

    const int t    = threadIdx.x;
    const int lane = t & 63;
    const int w    = t >> 6;
    const int n    = lane & 15;
    const int g    = lane >> 4;

    const int kend = (c0 + chunk_keys < q0 + BQ) ? c0 + chunk_keys : q0 + BQ;
    const int kt0  = c0 >> 6;
    const int kt1  = (kend + 63) >> 6;
    const int nch  = (q0 + BQ + chunk_keys - 1) / chunk_keys;

    const ushort* Qp = Q  + (size_t)b * S_LEN * 64;
    const ushort* Kp = K  + (size_t)b * S_LEN * 64;
    const ushort* Vp = Vt + (size_t)b * 64 * S_LEN;

    char* KsB = (char*)Ks;
    char* VsB = (char*)Vs;
    char* PsB = (char*)Ps + w * 2048;

    // Q A-frags (layout: row = lane&15, k = 32h + 8*(lane>>4) + i)
    L16 aq0, aq1;
    aq0.i = *reinterpret_cast<const int4*>(&Qp[(size_t)(q0 + 16 * w + n) * 64 + 8 * g]);
    aq1.i = *reinterpret_cast<const int4*>(&Qp[(size_t)(q0 + 16 * w + n) * 64 + 32 + 8 * g]);

    f32x4 oacc[4];
    float mrow[4], lrow[4];
    const f32x4 zero4 = {0.f, 0.f, 0.f, 0.f};
#pragma unroll
    for (int j = 0; j < 4; ++j) { oacc[j] = zero4; mrow[j] = -1e30f; lrow[j] = 0.f; }

    const int wqmin = q0 + 16 * w;
    const int wqmax = wqmin + 15;

    for (int kt = kt0; kt < kt1; ++kt) {
        const int k0 = kt << 6;
        __syncthreads();
        // stage K tile + V^T tile: global bf16 16B chunks -> swizzled LDS
#pragma unroll
        for (int r4 = 0; r4 < 4; ++r4) {
            int ch  = t + (r4 << 7);                 // 0..511
            int row = ch >> 3, c = ch & 7;
            int4 kv = *reinterpret_cast<const int4*>(&Kp[(size_t)(k0 + row) * 64 + c * 8]);
            int4 vv = *reinterpret_cast<const int4*>(&Vp[(size_t)row * S_LEN + k0 + c * 8]);
            *reinterpret_cast<int4*>(KsB + SWZ(row, c)) = kv;
            *reinterpret_cast<int4*>(VsB + SWZ(row, c)) = vv;
        }
        __syncthreads();
        if (k0 > wqmax) continue;   // fully-masked for this wave (barrier already done)

        // ---- QK^T: cS[t4] = S[16q x 16k] (C/D: row=g*4+j, col=n)
        f32x4 cS[4];
#pragma unroll
        for (int t4 = 0; t4 < 4; ++t4) {
            L16 b0, b1;
            b0.i = *reinterpret_cast<const int4*>(KsB + SWZ(16 * t4 + n, g));
            b1.i = *reinterpret_cast<const int4*>(KsB + SWZ(16 * t4 + n, 4 + g));
            f32x4 z = zero4;
            z      = __builtin_amdgcn_mfma_f32_16x16x32_bf16(aq0.s, b0.s, z, 0, 0, 0);
            cS[t4] = __builtin_amdgcn_mfma_f32_16x16x32_bf16(aq1.s, b1.s, z, 0, 0, 0);
        }

        // ---- scale + causal mask
        float sc[4][4];
#pragma unroll
        for (int t4 = 0; t4 < 4; ++t4)
#pragma unroll
            for (int j = 0; j < 4; ++j) sc[t4][j] = cS[t4][j] * 0.125f;

        if (k0 + 63 > wqmin) {
#pragma unroll
            for (int t4 = 0; t4 < 4; ++t4) {
                const int key = k0 + 16 * t4 + n;
#pragma unroll
                for (int j = 0; j < 4; ++j) {
                    const int q = wqmin + 4 * g + j;
                    if (key > q) sc[t4][j] = -1e30f;
                }
            }
        }

        // ---- online softmax (row = 4g+j; reduce over the 16 lanes of group g)
#pragma unroll
        for (int j = 0; j < 4; ++j) {
            float mx = fmaxf(fmaxf(sc[0][j], sc[1][j]), fmaxf(sc[2][j], sc[3][j]));
#pragma unroll
            for (int off = 1; off <= 8; off <<= 1) mx = fmaxf(mx, __shfl_xor(mx, off, 64));
            const float mnew  = fmaxf(mrow[j], mx);
            const float alpha = __expf(mrow[j] - mnew);
            const int   qrow  = 4 * g + j;
            float ps = 0.f;
#pragma unroll
            for (int t4 = 0; t4 < 4; ++t4) {
                const float p = __expf(sc[t4][j] - mnew);
                ps += p;
                *reinterpret_cast<ushort*>(PsB + SWZ(qrow, 2 * t4 + (n >> 3)) + (n & 7) * 2) = f2bf(p);
            }
#pragma unroll
            for (int off = 1; off <= 8; off <<= 1) ps += __shfl_xor(ps, off, 64);
            lrow[j] = lrow[j] * alpha + ps;
            mrow[j] = mnew;
            oacc[0][j] *= alpha; oacc[1][j] *= alpha;
            oacc[2][j] *= alpha; oacc[3][j] *= alpha;
        }

        // ---- PV: O[16q x 64d] += P[16q x 64k] * V[64k x 64d]
        asm volatile("s_waitcnt lgkmcnt(0)" ::: "memory");   // P writes -> A-frag reads
        L16 pa0, pa1;
        pa0.i = *reinterpret_cast<const int4*>(PsB + SWZ(n, g));
        pa1.i = *reinterpret_cast<const int4*>(PsB + SWZ(n, 4 + g));
#pragma unroll
        for (int nt = 0; nt < 4; ++nt) {
            L16 bv0, bv1;
            bv0.i = *reinterpret_cast<const int4*>(VsB + SWZ(16 * nt + n, g));
            bv1.i = *reinterpret_cast<const int4*>(VsB + SWZ(16 * nt + n, 4 + g));
            oacc[nt] = __builtin_amdgcn_mfma_f32_16x16x32_bf16(pa0.s, bv0.s, oacc[nt], 0, 0, 0);
            oacc[nt] = __builtin_amdgcn_mfma_f32_16x16x32_bf16(pa1.s, bv1.s, oacc[nt], 0, 0, 0);
        }
    }

    if (nch == 1) {
        // ---- direct write: O = oacc / l
#pragma unroll
        for (int j = 0; j < 4; ++j) {
            const float inv = 1.f / lrow[j];
            const int   q   = q0 + 16 * w + 4 * g + j;
#pragma unroll
            for (int nt = 0; nt < 4; ++nt)
                O[((size_t)b * S_LEN + q) * 64 + 16 * nt + n] = oacc[nt][j] * inv;
        }
    } else {
        // ---- partial write: unnormalized O, plus (m,l) per row
        const size_t slot = (size_t)blockIdx.x * NCH + blockIdx.y;
        float* op = Opart + slot * 2048;
#pragma unroll
        for (int j = 0; j < 4; ++j) {
            const int r = 16 * w + 4 * g + j;
#pragma unroll
            for (int nt = 0; nt < 4; ++nt)
                op[r * 64 + 16 * nt + n] = oacc[nt][j];
            if (n == 0) {
                Mpart[slot * 32 + r] = mrow[j];
                Lpart[slot * 32 + r] = lrow[j];
            }
        }
    }
}

// ---------------- split-K combine --------------------------------------------
__global__ __launch_bounds__(256) void reduce_kernel(
    const float* __restrict__ Opart, const float* __restrict__ Mpart,
    const float* __restrict__ Lpart, float* __restrict__ O,
    int NCH, int chunk_keys)
{
    const int bx  = blockIdx.x;
    const int b   = bx & 3;
    const int qt  = bx >> 2;
    const int q0  = qt * BQ;
    const int nch = (q0 + BQ + chunk_keys - 1) / chunk_keys;
    if (nch <= 1) return;               // attn wrote O directly

    const int t   = threadIdx.x;
    const int row = t >> 3;             // 0..31
    const int d0  = (t & 7) * 8;        // 0..56

    const size_t mbase = (size_t)bx * NCH * 32 + row;
    float mmax = -1e30f;
    for (int ch = 0; ch < nch; ++ch)
        mmax = fmaxf(mmax, Mpart[mbase + ch * 32]);

    float ltot = 0.f;
    float acc[8];
#pragma unroll
    for (int i = 0; i < 8; ++i) acc[i] = 0.f;

    for (int ch = 0; ch < nch; ++ch) {
        const float wgt = __expf(Mpart[mbase + ch * 32] - mmax);
        ltot += wgt * Lpart[mbase + ch * 32];
        const float* op = Opart + ((size_t)bx * NCH + ch) * 2048 + row * 64 + d0;
        const float4 a  = *reinterpret_cast<const float4*>(op);
        const float4 c4 = *reinterpret_cast<const float4*>(op + 4);
        acc[0] += wgt * a.x;  acc[1] += wgt * a.y;  acc[2] += wgt * a.z;  acc[3] += wgt * a.w;
        acc[4] += wgt * c4.x; acc[5] += wgt * c4.y; acc[6] += wgt * c4.z; acc[7] += wgt * c4.w;
    }
    const float inv = 1.f / ltot;
    float4 o0 = {acc[0] * inv, acc[1] * inv, acc[2] * inv, acc[3] * inv};
    float4 o1 = {acc[4] * inv, acc[5] * inv, acc[6] * inv, acc[7] * inv};
    float* dst = O + ((size_t)b * S_LEN + q0 + row) * 64 + d0;
    *reinterpret_cast<float4*>(dst)     = o0;
    *reinterpret_cast<float4*>(dst + 4) = o1;
}

extern "C" void kernel_launch(void* const* d_in, const int* in_sizes, int n_in,
                              void* d_out, int out_size, void* d_ws, size_t ws_size,
                              hipStream_t stream) {
    // setup_inputs() order: keys-X, values-X, queries-X, wq, wk, wv
    const float* Xk = (const float*)d_in[0];
    const float* Xv = (const float*)d_in[1];
    const float* Xq = (const float*)d_in[2];
    const float* wq = (const float*)d_in[3];
    const float* wk = (const float*)d_in[4];
    const float* wv = (const float*)d_in[5];
    float* out = (float*)d_out;

    // workspace: Q bf16 | K bf16 | V^T bf16 (2 MiB each) | split-K partials
    const size_t NEL = (size_t)BATCH * S_LEN * D_OUT;   // 1,048,576
    ushort* Qb  = (ushort*)d_ws;
    ushort* Kb  = Qb + NEL;
    ushort* Vtb = Kb + NEL;
    const size_t base_bytes = 3 * NEL * sizeof(ushort);           // 6,291,456
    const size_t per_nch    = (size_t)BATCH * NQT * (2048 + 64) * sizeof(float); // 4,325,376

    int NCH = 1;
    if      (ws_size >= base_bytes + 8 * per_nch) NCH = 8;
    else if (ws_size >= base_bytes + 4 * per_nch) NCH = 4;
    else if (ws_size >= base_bytes + 2 * per_nch) NCH = 2;
    const int chunk_keys = S_LEN / NCH;

    float* Opart = (float*)((char*)d_ws + base_bytes);
    float* Mpart = Opart + (size_t)BATCH * NQT * NCH * 2048;
    float* Lpart = Mpart + (size_t)BATCH * NQT * NCH * 32;

    dim3 pgrid(BATCH * S_LEN / 64, 3);
    proj_kernel<<<pgrid, 256, 0, stream>>>(Xq, Xk, Xv, wq, wk, wv, Qb, Kb, Vtb);

    dim3 agrid(BATCH * NQT, NCH);
    attn_kernel<<<agrid, 128, 0, stream>>>(Qb, Kb, Vtb, out, Opart, Mpart, Lpart,
                                           chunk_keys, NCH);
    if (NCH > 1)
        reduce_kernel<<<BATCH * NQT, 256, 0, stream>>>(Opart, Mpart, Lpart, out,
                                                       NCH, chunk_keys);
}

// Round 4
// 87.008 us; speedup vs baseline: 8.8875x; 1.1431x over previous
//
#include <hip/hip_runtime.h>

#define S_LEN 4096
#define D_IN 256
#define D_OUT 64
#define BATCH 4
#define BQ 64
#define NQT (S_LEN / BQ)   // 64 q-tiles per batch

typedef short bf16x8 __attribute__((ext_vector_type(8)));
typedef float f32x4 __attribute__((ext_vector_type(4)));

union L16 { int4 i; bf16x8 s; ushort u[8]; };

// byte offset into a [rows][128B] LDS tile (8x 16B chunks per row),
// XOR-swizzled per guide G4: chunk ^= (row & 7)
#define SWZ(row, chunk) (((row) << 7) + ((((chunk) ^ ((row) & 7))) << 4))

__device__ inline ushort f2bf(float x) {
    unsigned u = __builtin_bit_cast(unsigned, x);
    u += 0x7FFFu + ((u >> 16) & 1u);     // RNE
    return (ushort)(u >> 16);
}
__device__ inline float bf2f(ushort h) {
    return __builtin_bit_cast(float, (unsigned)h << 16);
}

// ---------------- W transpose+cast: Wt[3][64 n][256 k] bf16 = W[k][n] -------
__global__ __launch_bounds__(256) void wsplit_kernel(
    const float* __restrict__ wq, const float* __restrict__ wk, const float* __restrict__ wv,
    ushort* __restrict__ Wt)
{
    const float* W = (blockIdx.y == 0) ? wq : (blockIdx.y == 1) ? wk : wv;
    __shared__ float Ws[64][68];
    const int t  = threadIdx.x;
    const int k0 = blockIdx.x * 64;
#pragma unroll
    for (int i = 0; i < 4; ++i) {
        int idx = t + i * 256;                 // 0..1023
        int r = idx >> 4, c4 = (idx & 15) * 4;
        *reinterpret_cast<float4*>(&Ws[r][c4]) =
            *reinterpret_cast<const float4*>(&W[(size_t)(k0 + r) * 64 + c4]);
    }
    __syncthreads();
    const int n = t >> 2, kc = t & 3;
    ushort h[16];
#pragma unroll
    for (int i = 0; i < 16; ++i) h[i] = f2bf(Ws[kc * 16 + i][n]);
    ushort* dst = Wt + ((size_t)blockIdx.y * 64 + n) * 256 + k0 + kc * 16;
    *reinterpret_cast<int4*>(dst)     = *reinterpret_cast<int4*>(h);
    *reinterpret_cast<int4*>(dst + 8) = *reinterpret_cast<int4*>(h + 8);
}

// ---------------- projection via MFMA (X split hi/lo, W bf16) ---------------
// 64 rows/block, 4 waves (one 16-row m-tile each), K=256 in 8 steps of 32.
__global__ __launch_bounds__(256) void proj_kernel(
    const float* __restrict__ Xq, const float* __restrict__ Xk, const float* __restrict__ Xv,
    const ushort* __restrict__ Wt,
    ushort* __restrict__ Qb, ushort* __restrict__ Kb, ushort* __restrict__ Vtb)
{
    const float* X = (blockIdx.y == 0) ? Xq : (blockIdx.y == 1) ? Xk : Xv;
    const ushort* Wtp = Wt + (size_t)blockIdx.y * 64 * 256;

    __shared__ __align__(16) char XsB[64 * 128];    // X tile [64][32] f32, swizzled
    __shared__ __align__(16) ushort Ob[64][64];     // output bounce

    const int t    = threadIdx.x;
    const int lane = t & 63;
    const int w    = t >> 6;
    const int n    = lane & 15;
    const int g    = lane >> 4;
    const int row0 = blockIdx.x * 64;

    const int rsa = t >> 3, ca = t & 7;
    const float* xa = X + (size_t)(row0 + rsa) * D_IN + ca * 4;
    const float* xb = xa + (size_t)32 * D_IN;

    f32x4 acc[4];
    const f32x4 zero4 = {0.f, 0.f, 0.f, 0.f};
#pragma unroll
    for (int nt = 0; nt < 4; ++nt) acc[nt] = zero4;

    float4 pa = *reinterpret_cast<const float4*>(xa);
    float4 pb = *reinterpret_cast<const float4*>(xb);

    for (int kt = 0; kt < 8; ++kt) {
        __syncthreads();
        *reinterpret_cast<float4*>(XsB + SWZ(rsa, ca))      = pa;
        *reinterpret_cast<float4*>(XsB + SWZ(32 + rsa, ca)) = pb;
        if (kt < 7) {
            pa = *reinterpret_cast<const float4*>(xa + (kt + 1) * 32);
            pb = *reinterpret_cast<const float4*>(xb + (kt + 1) * 32);
        }
        __syncthreads();

        // B-frags from global (L2-resident W^T)
        L16 wb[4];
#pragma unroll
        for (int nt = 0; nt < 4; ++nt)
            wb[nt].i = *reinterpret_cast<const int4*>(&Wtp[(size_t)(16 * nt + n) * 256 + kt * 32 + 8 * g]);

        // A-frag: 8 f32 -> bf16 hi + lo
        const int r = 16 * w + n;
        float4 c0 = *reinterpret_cast<const float4*>(XsB + SWZ(r, 2 * g));
        float4 c1 = *reinterpret_cast<const float4*>(XsB + SWZ(r, 2 * g + 1));
        float xv[8] = {c0.x, c0.y, c0.z, c0.w, c1.x, c1.y, c1.z, c1.w};
        L16 xh, xl;
#pragma unroll
        for (int i = 0; i < 8; ++i) {
            ushort h = f2bf(xv[i]);
            xh.u[i] = h;
            xl.u[i] = f2bf(xv[i] - bf2f(h));
        }

#pragma unroll
        for (int nt = 0; nt < 4; ++nt) {
            acc[nt] = __builtin_amdgcn_mfma_f32_16x16x32_bf16(xh.s, wb[nt].s, acc[nt], 0, 0, 0);
            acc[nt] = __builtin_amdgcn_mfma_f32_16x16x32_bf16(xl.s, wb[nt].s, acc[nt], 0, 0, 0);
        }
    }

    // epilogue: bounce through LDS for coalesced bf16 stores (V transposed)
    const bool isV = (blockIdx.y == 2);
#pragma unroll
    for (int j = 0; j < 4; ++j) {
#pragma unroll
        for (int nt = 0; nt < 4; ++nt) {
            ushort h = f2bf(acc[nt][j]);
            int r = 16 * w + 4 * g + j;     // m-row in block
            int c = 16 * nt + n;            // output column
            if (isV) Ob[c][r] = h; else Ob[r][c] = h;
        }
    }
    __syncthreads();
    const int b  = row0 >> 12;
    const int s0 = row0 & 4095;
#pragma unroll
    for (int i = 0; i < 2; ++i) {
        int idx = t + i * 256;              // 0..511
        int r = idx >> 3, c8 = (idx & 7) * 8;
        int4 v = *reinterpret_cast<const int4*>(&Ob[r][c8]);
        if (blockIdx.y == 0)
            *reinterpret_cast<int4*>(&Qb[(size_t)(row0 + r) * 64 + c8]) = v;
        else if (blockIdx.y == 1)
            *reinterpret_cast<int4*>(&Kb[(size_t)(row0 + r) * 64 + c8]) = v;
        else
            *reinterpret_cast<int4*>(&Vtb[((size_t)b * 64 + r) * S_LEN + s0 + c8]) = v;
    }
}

// ---------------- causal flash attention, bf16 MFMA, split-K ----------------
// grid = (BATCH*NQT, NCH); 4 waves, wave w owns q-rows q0+16w..+15.
__global__ __launch_bounds__(256) void attn_kernel(
    const ushort* __restrict__ Q, const ushort* __restrict__ K,
    const ushort* __restrict__ Vt, float* __restrict__ O,
    float* __restrict__ Opart, float* __restrict__ Mpart, float* __restrict__ Lpart,
    int chunk_keys, int NCH)
{
    __shared__ __align__(16) ushort Ks[64 * 64];       // K tile  [key][d], swizzled
    __shared__ __align__(16) ushort Vs[64 * 64];       // V^T tile [d][key], swizzled
    __shared__ __align__(16) ushort Ps[4 * 16 * 64];   // per-wave P [q][key], swizzled

    const int b  = blockIdx.x & 3;
    const int qt = blockIdx.x >> 2;
    const int q0 = qt * BQ;
    const int c0 = blockIdx.y * chunk_keys;
    if (c0 >= q0 + BQ) return;           // chunk entirely above diagonal

    const int t    = threadIdx.x;
    const int lane = t & 63;
    const int w    = t >> 6;
    const int n    = lane & 15;
    const int g    = lane >> 4;

    const int kend = (c0 + chunk_keys < q0 + BQ) ? c0 + chunk_keys : q0 + BQ;
    const int kt0  = c0 >> 6;
    const int kt1  = (kend + 63) >> 6;
    const int nch  = (q0 + BQ + chunk_keys - 1) / chunk_keys;

    const ushort* Qp = Q  + (size_t)b * S_LEN * 64;
    const ushort* Kp = K  + (size_t)b * S_LEN * 64;
    const ushort* Vp = Vt + (size_t)b * 64 * S_LEN;

    char* KsB = (char*)Ks;
    char* VsB = (char*)Vs;
    char* PsB = (char*)Ps + w * 2048;

    // Q A-frags
    L16 aq0, aq1;
    aq0.i = *reinterpret_cast<const int4*>(&Qp[(size_t)(q0 + 16 * w + n) * 64 + 8 * g]);
    aq1.i = *reinterpret_cast<const int4*>(&Qp[(size_t)(q0 + 16 * w + n) * 64 + 32 + 8 * g]);

    // all-ones B-frag for the MFMA row-sum
    L16 ones;
    ones.i = make_int4(0x3F803F80, 0x3F803F80, 0x3F803F80, 0x3F803F80);

    f32x4 oacc[4];
    float mrow[4], lrow[4];
    const f32x4 zero4 = {0.f, 0.f, 0.f, 0.f};
#pragma unroll
    for (int j = 0; j < 4; ++j) { oacc[j] = zero4; mrow[j] = -1e30f; lrow[j] = 0.f; }

    const int wqmin = q0 + 16 * w;
    const int wqmax = wqmin + 15;

    const int srow = t >> 3, sc = t & 7;   // staging: thread covers rows srow, srow+32

    // prologue prefetch (tile kt0)
    int4 kv[2], vv[2];
    {
        const int k0 = kt0 << 6;
#pragma unroll
        for (int i = 0; i < 2; ++i) {
            int row = srow + i * 32;
            kv[i] = *reinterpret_cast<const int4*>(&Kp[(size_t)(k0 + row) * 64 + sc * 8]);
            vv[i] = *reinterpret_cast<const int4*>(&Vp[(size_t)row * S_LEN + k0 + sc * 8]);
        }
    }

    for (int kt = kt0; kt < kt1; ++kt) {
        const int k0 = kt << 6;
        __syncthreads();                     // prior tile's LDS reads done
#pragma unroll
        for (int i = 0; i < 2; ++i) {
            int row = srow + i * 32;
            *reinterpret_cast<int4*>(KsB + SWZ(row, sc)) = kv[i];
            *reinterpret_cast<int4*>(VsB + SWZ(row, sc)) = vv[i];
        }
        if (kt + 1 < kt1) {                  // prefetch next tile into regs
            const int k0n = (kt + 1) << 6;
#pragma unroll
            for (int i = 0; i < 2; ++i) {
                int row = srow + i * 32;
                kv[i] = *reinterpret_cast<const int4*>(&Kp[(size_t)(k0n + row) * 64 + sc * 8]);
                vv[i] = *reinterpret_cast<const int4*>(&Vp[(size_t)row * S_LEN + k0n + sc * 8]);
            }
        }
        __syncthreads();
        if (k0 > wqmax) continue;            // fully masked for this wave

        // ---- QK^T: cS[t4] = S[16q x 16k] (C/D: row=g*4+j, col=n)
        f32x4 cS[4];
#pragma unroll
        for (int t4 = 0; t4 < 4; ++t4) {
            L16 b0, b1;
            b0.i = *reinterpret_cast<const int4*>(KsB + SWZ(16 * t4 + n, g));
            b1.i = *reinterpret_cast<const int4*>(KsB + SWZ(16 * t4 + n, 4 + g));
            f32x4 z = zero4;
            z      = __builtin_amdgcn_mfma_f32_16x16x32_bf16(aq0.s, b0.s, z, 0, 0, 0);
            cS[t4] = __builtin_amdgcn_mfma_f32_16x16x32_bf16(aq1.s, b1.s, z, 0, 0, 0);
        }

        // ---- scale + causal mask
        float sc4[4][4];
#pragma unroll
        for (int t4 = 0; t4 < 4; ++t4)
#pragma unroll
            for (int j = 0; j < 4; ++j) sc4[t4][j] = cS[t4][j] * 0.125f;

        if (k0 + 63 > wqmin) {
#pragma unroll
            for (int t4 = 0; t4 < 4; ++t4) {
                const int key = k0 + 16 * t4 + n;
#pragma unroll
                for (int j = 0; j < 4; ++j) {
                    const int q = wqmin + 4 * g + j;
                    if (key > q) sc4[t4][j] = -1e30f;
                }
            }
        }

        // ---- online softmax: max-reduce + P-store; l via MFMA row-sum below
        float alpha_s[4];
#pragma unroll
        for (int j = 0; j < 4; ++j) {
            float mx = fmaxf(fmaxf(sc4[0][j], sc4[1][j]), fmaxf(sc4[2][j], sc4[3][j]));
#pragma unroll
            for (int off = 1; off <= 8; off <<= 1) mx = fmaxf(mx, __shfl_xor(mx, off, 64));
            const float mnew = fmaxf(mrow[j], mx);
            alpha_s[j] = __expf(mrow[j] - mnew);
            mrow[j] = mnew;
            const int qrow = 4 * g + j;
#pragma unroll
            for (int t4 = 0; t4 < 4; ++t4) {
                const float p = __expf(sc4[t4][j] - mnew);
                *reinterpret_cast<ushort*>(PsB + SWZ(qrow, 2 * t4 + (n >> 3)) + (n & 7) * 2) = f2bf(p);
            }
            oacc[0][j] *= alpha_s[j]; oacc[1][j] *= alpha_s[j];
            oacc[2][j] *= alpha_s[j]; oacc[3][j] *= alpha_s[j];
        }

        // ---- PV + row-sum: O += P*V ; l = l*alpha + P·1
        asm volatile("s_waitcnt lgkmcnt(0)" ::: "memory");   // P writes -> A-frag reads
        L16 pa0, pa1;
        pa0.i = *reinterpret_cast<const int4*>(PsB + SWZ(n, g));
        pa1.i = *reinterpret_cast<const int4*>(PsB + SWZ(n, 4 + g));

        f32x4 lsum = zero4;
        lsum = __builtin_amdgcn_mfma_f32_16x16x32_bf16(pa0.s, ones.s, lsum, 0, 0, 0);
        lsum = __builtin_amdgcn_mfma_f32_16x16x32_bf16(pa1.s, ones.s, lsum, 0, 0, 0);

#pragma unroll
        for (int nt = 0; nt < 4; ++nt) {
            L16 bv0, bv1;
            bv0.i = *reinterpret_cast<const int4*>(VsB + SWZ(16 * nt + n, g));
            bv1.i = *reinterpret_cast<const int4*>(VsB + SWZ(16 * nt + n, 4 + g));
            oacc[nt] = __builtin_amdgcn_mfma_f32_16x16x32_bf16(pa0.s, bv0.s, oacc[nt], 0, 0, 0);
            oacc[nt] = __builtin_amdgcn_mfma_f32_16x16x32_bf16(pa1.s, bv1.s, oacc[nt], 0, 0, 0);
        }
#pragma unroll
        for (int j = 0; j < 4; ++j) lrow[j] = lrow[j] * alpha_s[j] + lsum[j];
    }

    if (nch == 1) {
#pragma unroll
        for (int j = 0; j < 4; ++j) {
            const float inv = 1.f / lrow[j];
            const int   q   = q0 + 16 * w + 4 * g + j;
#pragma unroll
            for (int nt = 0; nt < 4; ++nt)
                O[((size_t)b * S_LEN + q) * 64 + 16 * nt + n] = oacc[nt][j] * inv;
        }
    } else {
        const size_t slot = (size_t)blockIdx.x * NCH + blockIdx.y;
        float* op = Opart + slot * (BQ * 64);
#pragma unroll
        for (int j = 0; j < 4; ++j) {
            const int r = 16 * w + 4 * g + j;
#pragma unroll
            for (int nt = 0; nt < 4; ++nt)
                op[r * 64 + 16 * nt + n] = oacc[nt][j];
            if (n == 0) {
                Mpart[slot * BQ + r] = mrow[j];
                Lpart[slot * BQ + r] = lrow[j];
            }
        }
    }
}

// ---------------- split-K combine --------------------------------------------
__global__ __launch_bounds__(256) void reduce_kernel(
    const float* __restrict__ Opart, const float* __restrict__ Mpart,
    const float* __restrict__ Lpart, float* __restrict__ O,
    int NCH, int chunk_keys)
{
    const int bx  = blockIdx.x;
    const int b   = bx & 3;
    const int qt  = bx >> 2;
    const int q0  = qt * BQ;
    const int nch = (q0 + BQ + chunk_keys - 1) / chunk_keys;
    if (nch <= 1) return;               // attn wrote O directly

    const int t   = threadIdx.x;
    const int row = t >> 2;             // 0..63
    const int d0  = (t & 3) * 16;       // 0..48

    const size_t mbase = (size_t)bx * NCH * BQ + row;
    float mmax = -1e30f;
    for (int ch = 0; ch < nch; ++ch)
        mmax = fmaxf(mmax, Mpart[mbase + (size_t)ch * BQ]);

    float ltot = 0.f;
    float4 acc[4];
#pragma unroll
    for (int i = 0; i < 4; ++i) acc[i] = make_float4(0.f, 0.f, 0.f, 0.f);

    for (int ch = 0; ch < nch; ++ch) {
        const float wgt = __expf(Mpart[mbase + (size_t)ch * BQ] - mmax);
        ltot += wgt * Lpart[mbase + (size_t)ch * BQ];
        const float* op = Opart + ((size_t)bx * NCH + ch) * (BQ * 64) + row * 64 + d0;
#pragma unroll
        for (int i = 0; i < 4; ++i) {
            const float4 a = *reinterpret_cast<const float4*>(op + i * 4);
            acc[i].x += wgt * a.x; acc[i].y += wgt * a.y;
            acc[i].z += wgt * a.z; acc[i].w += wgt * a.w;
        }
    }
    const float inv = 1.f / ltot;
    float* dst = O + ((size_t)b * S_LEN + q0 + row) * 64 + d0;
#pragma unroll
    for (int i = 0; i < 4; ++i) {
        float4 o = make_float4(acc[i].x * inv, acc[i].y * inv, acc[i].z * inv, acc[i].w * inv);
        *reinterpret_cast<float4*>(dst + i * 4) = o;
    }
}

extern "C" void kernel_launch(void* const* d_in, const int* in_sizes, int n_in,
                              void* d_out, int out_size, void* d_ws, size_t ws_size,
                              hipStream_t stream) {
    // setup_inputs() order: keys-X, values-X, queries-X, wq, wk, wv
    const float* Xk = (const float*)d_in[0];
    const float* Xv = (const float*)d_in[1];
    const float* Xq = (const float*)d_in[2];
    const float* wq = (const float*)d_in[3];
    const float* wk = (const float*)d_in[4];
    const float* wv = (const float*)d_in[5];
    float* out = (float*)d_out;

    // workspace: Q bf16 | K bf16 | V^T bf16 (2 MiB each) | {Wt (dead after proj)
    // aliasing Opart} | Mpart | Lpart
    const size_t NEL = (size_t)BATCH * S_LEN * D_OUT;   // 1,048,576
    ushort* Qb  = (ushort*)d_ws;
    ushort* Kb  = Qb + NEL;
    ushort* Vtb = Kb + NEL;
    const size_t base_bytes = 3 * NEL * sizeof(ushort);               // 6,291,456
    const size_t per_nch    = (size_t)BATCH * NQT * (BQ * 64 + 2 * BQ) * sizeof(float);

    int NCH = 1;
    if      (ws_size >= base_bytes + 8 * per_nch) NCH = 8;
    else if (ws_size >= base_bytes + 4 * per_nch) NCH = 4;
    else if (ws_size >= base_bytes + 2 * per_nch) NCH = 2;
    const int chunk_keys = S_LEN / NCH;

    ushort* Wt   = (ushort*)((char*)d_ws + base_bytes);   // aliases Opart
    float* Opart = (float*)((char*)d_ws + base_bytes);
    float* Mpart = Opart + (size_t)BATCH * NQT * NCH * (BQ * 64);
    float* Lpart = Mpart + (size_t)BATCH * NQT * NCH * BQ;

    wsplit_kernel<<<dim3(4, 3), 256, 0, stream>>>(wq, wk, wv, Wt);

    proj_kernel<<<dim3(BATCH * S_LEN / 64, 3), 256, 0, stream>>>(
        Xq, Xk, Xv, Wt, Qb, Kb, Vtb);

    dim3 agrid(BATCH * NQT, NCH);
    attn_kernel<<<agrid, 256, 0, stream>>>(Qb, Kb, Vtb, out, Opart, Mpart, Lpart,
                                           chunk_keys, NCH);
    if (NCH > 1)
        reduce_kernel<<<BATCH * NQT, 256, 0, stream>>>(Opart, Mpart, Lpart, out,
                                                       NCH, chunk_keys);
}

// Round 5
// 86.999 us; speedup vs baseline: 8.8884x; 1.0001x over previous
//
#include <hip/hip_runtime.h>

#define S_LEN 4096
#define D_IN 256
#define D_OUT 64
#define BATCH 4
#define BQ 64
#define NQT (S_LEN / BQ)   // 64 q-tiles per batch

typedef short bf16x8 __attribute__((ext_vector_type(8)));
typedef float f32x4 __attribute__((ext_vector_type(4)));

union L16 { int4 i; bf16x8 s; ushort u[8]; };

// byte offset into a [rows][128B] LDS tile (8x 16B chunks per row),
// XOR-swizzled per guide G4: chunk ^= (row & 7)
#define SWZ(row, chunk) (((row) << 7) + ((((chunk) ^ ((row) & 7))) << 4))

__device__ inline ushort f2bf(float x) {
    unsigned u = __builtin_bit_cast(unsigned, x);
    u += 0x7FFFu + ((u >> 16) & 1u);     // RNE
    return (ushort)(u >> 16);
}
__device__ inline float bf2f(ushort h) {
    return __builtin_bit_cast(float, (unsigned)h << 16);
}

// ---------------- W transpose+cast: Wt[3][64 n][256 k] bf16 = W[k][n] -------
__global__ __launch_bounds__(256) void wsplit_kernel(
    const float* __restrict__ wq, const float* __restrict__ wk, const float* __restrict__ wv,
    ushort* __restrict__ Wt)
{
    const float* W = (blockIdx.y == 0) ? wq : (blockIdx.y == 1) ? wk : wv;
    __shared__ float Ws[64][68];
    const int t  = threadIdx.x;
    const int k0 = blockIdx.x * 64;
#pragma unroll
    for (int i = 0; i < 4; ++i) {
        int idx = t + i * 256;                 // 0..1023
        int r = idx >> 4, c4 = (idx & 15) * 4;
        *reinterpret_cast<float4*>(&Ws[r][c4]) =
            *reinterpret_cast<const float4*>(&W[(size_t)(k0 + r) * 64 + c4]);
    }
    __syncthreads();
    const int n = t >> 2, kc = t & 3;
    ushort h[16];
#pragma unroll
    for (int i = 0; i < 16; ++i) h[i] = f2bf(Ws[kc * 16 + i][n]);
    ushort* dst = Wt + ((size_t)blockIdx.y * 64 + n) * 256 + k0 + kc * 16;
    *reinterpret_cast<int4*>(dst)     = *reinterpret_cast<int4*>(h);
    *reinterpret_cast<int4*>(dst + 8) = *reinterpret_cast<int4*>(h + 8);
}

// ---------------- projection via MFMA (X split hi/lo, W bf16) ---------------
// 64 rows/block, 4 waves (one 16-row m-tile each), K=256 in 8 steps of 32.
__global__ __launch_bounds__(256) void proj_kernel(
    const float* __restrict__ Xq, const float* __restrict__ Xk, const float* __restrict__ Xv,
    const ushort* __restrict__ Wt,
    ushort* __restrict__ Qb, ushort* __restrict__ Kb, ushort* __restrict__ Vtb)
{
    const float* X = (blockIdx.y == 0) ? Xq : (blockIdx.y == 1) ? Xk : Xv;
    const ushort* Wtp = Wt + (size_t)blockIdx.y * 64 * 256;

    __shared__ __align__(16) char XsB[64 * 128];    // X tile [64][32] f32, swizzled
    __shared__ __align__(16) ushort Ob[64][64];     // output bounce

    const int t    = threadIdx.x;
    const int lane = t & 63;
    const int w    = t >> 6;
    const int n    = lane & 15;
    const int g    = lane >> 4;
    const int row0 = blockIdx.x * 64;

    const int rsa = t >> 3, ca = t & 7;
    const float* xa = X + (size_t)(row0 + rsa) * D_IN + ca * 4;
    const float* xb = xa + (size_t)32 * D_IN;

    f32x4 acc[4];
    const f32x4 zero4 = {0.f, 0.f, 0.f, 0.f};
#pragma unroll
    for (int nt = 0; nt < 4; ++nt) acc[nt] = zero4;

    float4 pa = *reinterpret_cast<const float4*>(xa);
    float4 pb = *reinterpret_cast<const float4*>(xb);

    for (int kt = 0; kt < 8; ++kt) {
        __syncthreads();
        *reinterpret_cast<float4*>(XsB + SWZ(rsa, ca))      = pa;
        *reinterpret_cast<float4*>(XsB + SWZ(32 + rsa, ca)) = pb;
        if (kt < 7) {
            pa = *reinterpret_cast<const float4*>(xa + (kt + 1) * 32);
            pb = *reinterpret_cast<const float4*>(xb + (kt + 1) * 32);
        }
        __syncthreads();

        // B-frags from global (L2-resident W^T)
        L16 wb[4];
#pragma unroll
        for (int nt = 0; nt < 4; ++nt)
            wb[nt].i = *reinterpret_cast<const int4*>(&Wtp[(size_t)(16 * nt + n) * 256 + kt * 32 + 8 * g]);

        // A-frag: 8 f32 -> bf16 hi + lo
        const int r = 16 * w + n;
        float4 c0 = *reinterpret_cast<const float4*>(XsB + SWZ(r, 2 * g));
        float4 c1 = *reinterpret_cast<const float4*>(XsB + SWZ(r, 2 * g + 1));
        float xv[8] = {c0.x, c0.y, c0.z, c0.w, c1.x, c1.y, c1.z, c1.w};
        L16 xh, xl;
#pragma unroll
        for (int i = 0; i < 8; ++i) {
            ushort h = f2bf(xv[i]);
            xh.u[i] = h;
            xl.u[i] = f2bf(xv[i] - bf2f(h));
        }

#pragma unroll
        for (int nt = 0; nt < 4; ++nt) {
            acc[nt] = __builtin_amdgcn_mfma_f32_16x16x32_bf16(xh.s, wb[nt].s, acc[nt], 0, 0, 0);
            acc[nt] = __builtin_amdgcn_mfma_f32_16x16x32_bf16(xl.s, wb[nt].s, acc[nt], 0, 0, 0);
        }
    }

    // epilogue: bounce through LDS for coalesced bf16 stores (V transposed)
    const bool isV = (blockIdx.y == 2);
#pragma unroll
    for (int j = 0; j < 4; ++j) {
#pragma unroll
        for (int nt = 0; nt < 4; ++nt) {
            ushort h = f2bf(acc[nt][j]);
            int r = 16 * w + 4 * g + j;     // m-row in block
            int c = 16 * nt + n;            // output column
            if (isV) Ob[c][r] = h; else Ob[r][c] = h;
        }
    }
    __syncthreads();
    const int b  = row0 >> 12;
    const int s0 = row0 & 4095;
#pragma unroll
    for (int i = 0; i < 2; ++i) {
        int idx = t + i * 256;              // 0..511
        int r = idx >> 3, c8 = (idx & 7) * 8;
        int4 v = *reinterpret_cast<const int4*>(&Ob[r][c8]);
        if (blockIdx.y == 0)
            *reinterpret_cast<int4*>(&Qb[(size_t)(row0 + r) * 64 + c8]) = v;
        else if (blockIdx.y == 1)
            *reinterpret_cast<int4*>(&Kb[(size_t)(row0 + r) * 64 + c8]) = v;
        else
            *reinterpret_cast<int4*>(&Vtb[((size_t)b * 64 + r) * S_LEN + s0 + c8]) = v;
    }
}

// ---------------- causal flash attention, bf16 MFMA, split-K ----------------
// grid = (BATCH*NQT, NCH); 4 waves, wave w owns q-rows q0+16w..+15.
// qt reversed (LPT). Partials: O bf16, (m,l) f32.
__global__ __launch_bounds__(256) void attn_kernel(
    const ushort* __restrict__ Q, const ushort* __restrict__ K,
    const ushort* __restrict__ Vt, float* __restrict__ O,
    ushort* __restrict__ Opart, float* __restrict__ Mpart, float* __restrict__ Lpart,
    int chunk_keys, int NCH)
{
    __shared__ __align__(16) ushort Ks[64 * 64];       // K tile  [key][d], swizzled
    __shared__ __align__(16) ushort Vs[64 * 64];       // V^T tile [d][key], swizzled
    __shared__ __align__(16) ushort Ps[4 * 16 * 64];   // per-wave P [q][key], swizzled

    const int b  = blockIdx.x & 3;
    const int qt = (NQT - 1) - (blockIdx.x >> 2);      // LPT: longest first
    const int q0 = qt * BQ;
    const int c0 = blockIdx.y * chunk_keys;
    if (c0 >= q0 + BQ) return;           // chunk entirely above diagonal

    const int t    = threadIdx.x;
    const int lane = t & 63;
    const int w    = t >> 6;
    const int n    = lane & 15;
    const int g    = lane >> 4;

    const int kend = (c0 + chunk_keys < q0 + BQ) ? c0 + chunk_keys : q0 + BQ;
    const int kt0  = c0 >> 6;
    const int kt1  = (kend + 63) >> 6;
    const int nch  = (q0 + BQ + chunk_keys - 1) / chunk_keys;

    const ushort* Qp = Q  + (size_t)b * S_LEN * 64;
    const ushort* Kp = K  + (size_t)b * S_LEN * 64;
    const ushort* Vp = Vt + (size_t)b * 64 * S_LEN;

    char* KsB = (char*)Ks;
    char* VsB = (char*)Vs;
    char* PsB = (char*)Ps + w * 2048;

    // Q A-frags
    L16 aq0, aq1;
    aq0.i = *reinterpret_cast<const int4*>(&Qp[(size_t)(q0 + 16 * w + n) * 64 + 8 * g]);
    aq1.i = *reinterpret_cast<const int4*>(&Qp[(size_t)(q0 + 16 * w + n) * 64 + 32 + 8 * g]);

    // all-ones B-frag for the MFMA row-sum
    L16 ones;
    ones.i = make_int4(0x3F803F80, 0x3F803F80, 0x3F803F80, 0x3F803F80);

    f32x4 oacc[4];
    float mrow[4], lrow[4];
    const f32x4 zero4 = {0.f, 0.f, 0.f, 0.f};
#pragma unroll
    for (int j = 0; j < 4; ++j) { oacc[j] = zero4; mrow[j] = -1e30f; lrow[j] = 0.f; }

    const int wqmin = q0 + 16 * w;
    const int wqmax = wqmin + 15;

    const int srow = t >> 3, sc = t & 7;   // staging: thread covers rows srow, srow+32

    // prologue prefetch (tile kt0)
    int4 kv[2], vv[2];
    {
        const int k0 = kt0 << 6;
#pragma unroll
        for (int i = 0; i < 2; ++i) {
            int row = srow + i * 32;
            kv[i] = *reinterpret_cast<const int4*>(&Kp[(size_t)(k0 + row) * 64 + sc * 8]);
            vv[i] = *reinterpret_cast<const int4*>(&Vp[(size_t)row * S_LEN + k0 + sc * 8]);
        }
    }

    for (int kt = kt0; kt < kt1; ++kt) {
        const int k0 = kt << 6;
        __syncthreads();                     // prior tile's LDS reads done
#pragma unroll
        for (int i = 0; i < 2; ++i) {
            int row = srow + i * 32;
            *reinterpret_cast<int4*>(KsB + SWZ(row, sc)) = kv[i];
            *reinterpret_cast<int4*>(VsB + SWZ(row, sc)) = vv[i];
        }
        if (kt + 1 < kt1) {                  // prefetch next tile into regs
            const int k0n = (kt + 1) << 6;
#pragma unroll
            for (int i = 0; i < 2; ++i) {
                int row = srow + i * 32;
                kv[i] = *reinterpret_cast<const int4*>(&Kp[(size_t)(k0n + row) * 64 + sc * 8]);
                vv[i] = *reinterpret_cast<const int4*>(&Vp[(size_t)row * S_LEN + k0n + sc * 8]);
            }
        }
        __syncthreads();
        if (k0 > wqmax) continue;            // fully masked for this wave

        // ---- QK^T: cS[t4] = S[16q x 16k] (C/D: row=g*4+j, col=n)
        f32x4 cS[4];
#pragma unroll
        for (int t4 = 0; t4 < 4; ++t4) {
            L16 b0, b1;
            b0.i = *reinterpret_cast<const int4*>(KsB + SWZ(16 * t4 + n, g));
            b1.i = *reinterpret_cast<const int4*>(KsB + SWZ(16 * t4 + n, 4 + g));
            f32x4 z = zero4;
            z      = __builtin_amdgcn_mfma_f32_16x16x32_bf16(aq0.s, b0.s, z, 0, 0, 0);
            cS[t4] = __builtin_amdgcn_mfma_f32_16x16x32_bf16(aq1.s, b1.s, z, 0, 0, 0);
        }

        // ---- scale + causal mask
        float sc4[4][4];
#pragma unroll
        for (int t4 = 0; t4 < 4; ++t4)
#pragma unroll
            for (int j = 0; j < 4; ++j) sc4[t4][j] = cS[t4][j] * 0.125f;

        if (k0 + 63 > wqmin) {
#pragma unroll
            for (int t4 = 0; t4 < 4; ++t4) {
                const int key = k0 + 16 * t4 + n;
#pragma unroll
                for (int j = 0; j < 4; ++j) {
                    const int q = wqmin + 4 * g + j;
                    if (key > q) sc4[t4][j] = -1e30f;
                }
            }
        }

        // ---- online softmax: max-reduce + P-store; l via MFMA row-sum below
        float alpha_s[4];
#pragma unroll
        for (int j = 0; j < 4; ++j) {
            float mx = fmaxf(fmaxf(sc4[0][j], sc4[1][j]), fmaxf(sc4[2][j], sc4[3][j]));
#pragma unroll
            for (int off = 1; off <= 8; off <<= 1) mx = fmaxf(mx, __shfl_xor(mx, off, 64));
            const float mnew = fmaxf(mrow[j], mx);
            alpha_s[j] = __expf(mrow[j] - mnew);
            mrow[j] = mnew;
            const int qrow = 4 * g + j;
#pragma unroll
            for (int t4 = 0; t4 < 4; ++t4) {
                const float p = __expf(sc4[t4][j] - mnew);
                *reinterpret_cast<ushort*>(PsB + SWZ(qrow, 2 * t4 + (n >> 3)) + (n & 7) * 2) = f2bf(p);
            }
            oacc[0][j] *= alpha_s[j]; oacc[1][j] *= alpha_s[j];
            oacc[2][j] *= alpha_s[j]; oacc[3][j] *= alpha_s[j];
        }

        // ---- PV + row-sum: O += P*V ; l = l*alpha + P·1
        asm volatile("s_waitcnt lgkmcnt(0)" ::: "memory");   // P writes -> A-frag reads
        L16 pa0, pa1;
        pa0.i = *reinterpret_cast<const int4*>(PsB + SWZ(n, g));
        pa1.i = *reinterpret_cast<const int4*>(PsB + SWZ(n, 4 + g));

        f32x4 lsum = zero4;
        lsum = __builtin_amdgcn_mfma_f32_16x16x32_bf16(pa0.s, ones.s, lsum, 0, 0, 0);
        lsum = __builtin_amdgcn_mfma_f32_16x16x32_bf16(pa1.s, ones.s, lsum, 0, 0, 0);

#pragma unroll
        for (int nt = 0; nt < 4; ++nt) {
            L16 bv0, bv1;
            bv0.i = *reinterpret_cast<const int4*>(VsB + SWZ(16 * nt + n, g));
            bv1.i = *reinterpret_cast<const int4*>(VsB + SWZ(16 * nt + n, 4 + g));
            oacc[nt] = __builtin_amdgcn_mfma_f32_16x16x32_bf16(pa0.s, bv0.s, oacc[nt], 0, 0, 0);
            oacc[nt] = __builtin_amdgcn_mfma_f32_16x16x32_bf16(pa1.s, bv1.s, oacc[nt], 0, 0, 0);
        }
#pragma unroll
        for (int j = 0; j < 4; ++j) lrow[j] = lrow[j] * alpha_s[j] + lsum[j];
    }

    if (nch == 1) {
#pragma unroll
        for (int j = 0; j < 4; ++j) {
            const float inv = 1.f / lrow[j];
            const int   q   = q0 + 16 * w + 4 * g + j;
#pragma unroll
            for (int nt = 0; nt < 4; ++nt)
                O[((size_t)b * S_LEN + q) * 64 + 16 * nt + n] = oacc[nt][j] * inv;
        }
    } else {
        // canonical slot (independent of the LPT blockIdx mapping)
        const size_t slot = (size_t)((qt << 2) | b) * NCH + blockIdx.y;
        // bf16 partial O: bounce through this wave's P buffer, then 16B stores
        ushort* pb = (ushort*)PsB;           // plain [16][64] layout
#pragma unroll
        for (int j = 0; j < 4; ++j)
#pragma unroll
            for (int nt = 0; nt < 4; ++nt)
                pb[(4 * g + j) * 64 + 16 * nt + n] = f2bf(oacc[nt][j]);
        ushort* dst = Opart + slot * (BQ * 64) + w * 1024;
#pragma unroll
        for (int i = 0; i < 2; ++i) {
            int ii = i * 64 + lane;          // int4 index within the wave's 2 KB
            *reinterpret_cast<int4*>(dst + ii * 8) =
                *reinterpret_cast<const int4*>(pb + ii * 8);
        }
        if (n == 0) {
#pragma unroll
            for (int j = 0; j < 4; ++j) {
                const int r = 16 * w + 4 * g + j;
                Mpart[slot * BQ + r] = mrow[j];
                Lpart[slot * BQ + r] = lrow[j];
            }
        }
    }
}

// ---------------- split-K combine (bf16 partials) ---------------------------
__global__ __launch_bounds__(256) void reduce_kernel(
    const ushort* __restrict__ Opart, const float* __restrict__ Mpart,
    const float* __restrict__ Lpart, float* __restrict__ O,
    int NCH, int chunk_keys)
{
    const int bx  = blockIdx.x;
    const int b   = bx & 3;
    const int qt  = bx >> 2;
    const int q0  = qt * BQ;
    const int nch = (q0 + BQ + chunk_keys - 1) / chunk_keys;
    if (nch <= 1) return;               // attn wrote O directly

    const int t   = threadIdx.x;
    const int row = t >> 2;             // 0..63
    const int d0  = (t & 3) * 16;       // 0..48

    const size_t mbase = (size_t)bx * NCH * BQ + row;
    float mmax = -1e30f;
    for (int ch = 0; ch < nch; ++ch)
        mmax = fmaxf(mmax, Mpart[mbase + (size_t)ch * BQ]);

    float ltot = 0.f;
    float acc[16];
#pragma unroll
    for (int i = 0; i < 16; ++i) acc[i] = 0.f;

    for (int ch = 0; ch < nch; ++ch) {
        const float wgt = __expf(Mpart[mbase + (size_t)ch * BQ] - mmax);
        ltot += wgt * Lpart[mbase + (size_t)ch * BQ];
        const ushort* op = Opart + ((size_t)bx * NCH + ch) * (BQ * 64) + row * 64 + d0;
        L16 v0, v1;
        v0.i = *reinterpret_cast<const int4*>(op);
        v1.i = *reinterpret_cast<const int4*>(op + 8);
#pragma unroll
        for (int i = 0; i < 8; ++i) {
            acc[i]     += wgt * bf2f(v0.u[i]);
            acc[i + 8] += wgt * bf2f(v1.u[i]);
        }
    }
    const float inv = 1.f / ltot;
    float* dst = O + ((size_t)b * S_LEN + q0 + row) * 64 + d0;
#pragma unroll
    for (int i = 0; i < 4; ++i) {
        float4 o = make_float4(acc[4 * i] * inv, acc[4 * i + 1] * inv,
                               acc[4 * i + 2] * inv, acc[4 * i + 3] * inv);
        *reinterpret_cast<float4*>(dst + i * 4) = o;
    }
}

extern "C" void kernel_launch(void* const* d_in, const int* in_sizes, int n_in,
                              void* d_out, int out_size, void* d_ws, size_t ws_size,
                              hipStream_t stream) {
    // setup_inputs() order: keys-X, values-X, queries-X, wq, wk, wv
    const float* Xk = (const float*)d_in[0];
    const float* Xv = (const float*)d_in[1];
    const float* Xq = (const float*)d_in[2];
    const float* wq = (const float*)d_in[3];
    const float* wk = (const float*)d_in[4];
    const float* wv = (const float*)d_in[5];
    float* out = (float*)d_out;

    // workspace: Q bf16 | K bf16 | V^T bf16 (2 MiB each) | {Wt (dead after
    // proj) aliasing Opart} | Mpart | Lpart
    const size_t NEL = (size_t)BATCH * S_LEN * D_OUT;   // 1,048,576
    ushort* Qb  = (ushort*)d_ws;
    ushort* Kb  = Qb + NEL;
    ushort* Vtb = Kb + NEL;
    const size_t base_bytes = 3 * NEL * sizeof(ushort);               // 6,291,456
    const size_t per_nch    = (size_t)BATCH * NQT *
                              (BQ * 64 * sizeof(ushort) + 2 * BQ * sizeof(float));

    int NCH = 1;
    if      (ws_size >= base_bytes + 16 * per_nch) NCH = 16;
    else if (ws_size >= base_bytes +  8 * per_nch) NCH = 8;
    else if (ws_size >= base_bytes +  4 * per_nch) NCH = 4;
    else if (ws_size >= base_bytes +  2 * per_nch) NCH = 2;
    const int chunk_keys = S_LEN / NCH;

    ushort* Wt    = (ushort*)((char*)d_ws + base_bytes);   // aliases Opart
    ushort* Opart = (ushort*)((char*)d_ws + base_bytes);
    float*  Mpart = (float*)((char*)d_ws + base_bytes +
                             (size_t)BATCH * NQT * NCH * BQ * 64 * sizeof(ushort));
    float*  Lpart = Mpart + (size_t)BATCH * NQT * NCH * BQ;

    wsplit_kernel<<<dim3(4, 3), 256, 0, stream>>>(wq, wk, wv, Wt);

    proj_kernel<<<dim3(BATCH * S_LEN / 64, 3), 256, 0, stream>>>(
        Xq, Xk, Xv, Wt, Qb, Kb, Vtb);

    dim3 agrid(BATCH * NQT, NCH);
    attn_kernel<<<agrid, 256, 0, stream>>>(Qb, Kb, Vtb, out, Opart, Mpart, Lpart,
                                           chunk_keys, NCH);
    if (NCH > 1)
        reduce_kernel<<<BATCH * NQT, 256, 0, stream>>>(Opart, Mpart, Lpart, out,
                                                       NCH, chunk_keys);
}